// Round 1
// baseline (326.722 us; speedup 1.0000x reference)
//
#include <hip/hip_runtime.h>

#define BATCH 200000
#define DD 16
#define LIB 969   // 1 + 16 + 136 + 816
#define NQ_BASE (1 + DD)                      // 17: first quadratic row
#define NC_BASE (1 + DD + (DD*(DD+1))/2)      // 153: first cubic row

// ---------------- prep: coeffs_full = where(mask, fixed, coeff) ----------------
__global__ __launch_bounds__(256) void prep_coeffs(
    const float* __restrict__ coeff,
    const float* __restrict__ fixedv,
    const unsigned char* __restrict__ mask,   // numpy bool = 1 byte
    float* __restrict__ cf, int n) {
  int i = blockIdx.x * 256 + threadIdx.x;
  if (i < n) cf[i] = mask[i] ? fixedv[i] : coeff[i];
}

// ---------------- main kernel ----------------
__device__ __forceinline__ void fma16(float p, const float4* __restrict__ cr,
                                      float4& a0, float4& a1, float4& a2, float4& a3) {
  float4 w0 = cr[0], w1 = cr[1], w2 = cr[2], w3 = cr[3];
  a0.x = fmaf(p, w0.x, a0.x); a0.y = fmaf(p, w0.y, a0.y);
  a0.z = fmaf(p, w0.z, a0.z); a0.w = fmaf(p, w0.w, a0.w);
  a1.x = fmaf(p, w1.x, a1.x); a1.y = fmaf(p, w1.y, a1.y);
  a1.z = fmaf(p, w1.z, a1.z); a1.w = fmaf(p, w1.w, a1.w);
  a2.x = fmaf(p, w2.x, a2.x); a2.y = fmaf(p, w2.y, a2.y);
  a2.z = fmaf(p, w2.z, a2.z); a2.w = fmaf(p, w2.w, a2.w);
  a3.x = fmaf(p, w3.x, a3.x); a3.y = fmaf(p, w3.y, a3.y);
  a3.z = fmaf(p, w3.z, a3.z); a3.w = fmaf(p, w3.w, a3.w);
}

__global__ __launch_bounds__(256) void sindy_main(
    const float* __restrict__ z,     // [BATCH, 16]
    const float* __restrict__ cf,    // [LIB, 16] fused coeffs
    float* __restrict__ out) {       // [BATCH, 16]
  // z staged transposed in LDS so runtime-k access zs[k][tid] stays out of
  // scratch; lane-consecutive addresses -> conflict-free (2 lanes/bank, free).
  __shared__ float zs[DD][256];
  const int tid = threadIdx.x;
  const long long row = (long long)blockIdx.x * 256 + tid;
  const bool valid = (row < BATCH);

  float4 z0 = make_float4(0.f, 0.f, 0.f, 0.f), z1 = z0, z2 = z0, z3 = z0;
  if (valid) {
    const float4* zp = (const float4*)(z + row * DD);   // 64B-aligned
    z0 = zp[0]; z1 = zp[1]; z2 = zp[2]; z3 = zp[3];
  }
  zs[ 0][tid] = z0.x; zs[ 1][tid] = z0.y; zs[ 2][tid] = z0.z; zs[ 3][tid] = z0.w;
  zs[ 4][tid] = z1.x; zs[ 5][tid] = z1.y; zs[ 6][tid] = z1.z; zs[ 7][tid] = z1.w;
  zs[ 8][tid] = z2.x; zs[ 9][tid] = z2.y; zs[10][tid] = z2.z; zs[11][tid] = z2.w;
  zs[12][tid] = z3.x; zs[13][tid] = z3.y; zs[14][tid] = z3.z; zs[15][tid] = z3.w;
  __syncthreads();

  const float4* c4 = (const float4*)cf;   // row t = c4 + t*4 (16 floats)

  // t = 0: constant feature (theta = 1) -> acc = coeff row 0
  float4 a0 = c4[0], a1 = c4[1], a2 = c4[2], a3 = c4[3];

  // linear features: rows 1..16
#pragma unroll 1
  for (int i = 0; i < DD; ++i) {
    fma16(zs[i][tid], c4 + (1 + i) * 4, a0, a1, a2, a3);
  }

  // quadratic (lex (i<=j), rows 17..152) and cubic (lex (i<=j<=k), rows 153..968)
  // two uniform counters keep coefficient-row order matched to the reference's
  // combinations_with_replacement ordering even though loops are interleaved.
  int tq = NQ_BASE;
  int tc = NC_BASE;
#pragma unroll 1
  for (int i = 0; i < DD; ++i) {
    const float zi = zs[i][tid];
#pragma unroll 1
    for (int j = i; j < DD; ++j) {
      const float p2 = zi * zs[j][tid];
      fma16(p2, c4 + tq * 4, a0, a1, a2, a3);
      ++tq;
      for (int k = j; k < DD; ++k) {
        const float p3 = p2 * zs[k][tid];
        fma16(p3, c4 + tc * 4, a0, a1, a2, a3);
        ++tc;
      }
    }
  }

  if (valid) {
    float4* op = (float4*)(out + row * DD);
    op[0] = a0; op[1] = a1; op[2] = a2; op[3] = a3;
  }
}

extern "C" void kernel_launch(void* const* d_in, const int* in_sizes, int n_in,
                              void* d_out, int out_size, void* d_ws, size_t ws_size,
                              hipStream_t stream) {
  const float* z      = (const float*)d_in[0];
  const float* coeff  = (const float*)d_in[1];
  const float* fixedv = (const float*)d_in[2];
  const unsigned char* mask = (const unsigned char*)d_in[3];
  float* out = (float*)d_out;
  float* cf  = (float*)d_ws;   // needs LIB*16*4 = 62016 B of scratch

  const int ncf = LIB * DD;
  prep_coeffs<<<(ncf + 255) / 256, 256, 0, stream>>>(coeff, fixedv, mask, cf, ncf);

  const int nblk = (BATCH + 255) / 256;
  sindy_main<<<nblk, 256, 0, stream>>>(z, cf, out);
}

// Round 4
// 109.139 us; speedup vs baseline: 2.9936x; 2.9936x over previous
//
#include <hip/hip_runtime.h>

#define BATCH 200000
#define DD 16
#define LIB 969          // 1 + 16 + 136 + 816
#define KPAD 1024        // features padded to 16 chunks of 64 (pad coeff rows = 0)
#define CHUNK 64         // features per LDS chunk
#define NCHUNK 16
#define A_STRIDE 144     // bytes/row/chunk: 64*2 + 16 pad -> 36 dw stride, 2-way conflicts (free)
#define B_STRIDE 2064    // bytes/B-row: 1024*2 + 16 pad -> 516 dw stride, 2-way
#define A_BYTES (256 * A_STRIDE)        // 36864
#define B_BYTES (DD * B_STRIDE)         // 33024
#define LDS_BYTES (A_BYTES + B_BYTES)   // 69888 -> 2 blocks/CU (ran fine in R3)

typedef short short8 __attribute__((ext_vector_type(8)));
typedef float f32x4 __attribute__((ext_vector_type(4)));

// ---- compile-time feature enumeration (matches combinations_with_replacement order) ----
struct FIdx { int a, b, c; };
constexpr FIdx feat_idx(int f) {
  if (f == 0) return FIdx{-1, -1, -1};               // constant 1
  if (f <= DD) return FIdx{f - 1, -1, -1};           // linear
  if (f < 1 + DD + DD * (DD + 1) / 2) {              // quadratic, lex (i<=j)
    int t = f - 1 - DD;
    for (int i = 0; i < DD; ++i) {
      if (t < DD - i) return FIdx{i, i + t, -1};
      t -= DD - i;
    }
  }
  if (f < LIB) {                                     // cubic, lex (i<=j<=k)
    int t = f - (1 + DD + DD * (DD + 1) / 2);
    for (int i = 0; i < DD; ++i)
      for (int j = i; j < DD; ++j) {
        if (t < DD - j) return FIdx{i, j, j + t};
        t -= DD - j;
      }
  }
  return FIdx{-2, -2, -2};                           // padding -> 0
}

template <int F>
__device__ __forceinline__ float fval(const float* z) {
  constexpr FIdx t = feat_idx(F);
  if constexpr (t.a == -2) return 0.0f;
  else if constexpr (t.a == -1) return 1.0f;
  else if constexpr (t.b == -1) return z[t.a];
  else if constexpr (t.c == -1) return z[t.a] * z[t.b];
  else return (z[t.a] * z[t.b]) * z[t.c];            // prefix CSE across k
}

// f32 -> bf16 RNE, two at a time, pure integer bit math (no __hip_bfloat162,
// which is not trivially copyable -> __builtin_bit_cast rejects it).
__device__ __forceinline__ unsigned int pk_bf16(float a, float b) {
  unsigned int ua = __builtin_bit_cast(unsigned int, a);
  unsigned int ub = __builtin_bit_cast(unsigned int, b);
  ua += 0x7fffu + ((ua >> 16) & 1u);   // round-to-nearest-even (finite inputs)
  ub += 0x7fffu + ((ub >> 16) & 1u);
  return (ua >> 16) | (ub & 0xffff0000u);
}

// 8 features -> 8 bf16 -> one ds_write_b128.
// NOTE: dst aliases the LDS tile that MFMA fragments are read from -> NO
// __restrict__ anywhere on these pointers (R3 bug: restrict let the scheduler
// hoist the fragment ds_reads above these ds_writes).
template <int F>
__device__ __forceinline__ void emit8(const float* z, char* dst) {
  float a0 = fval<F + 0>(z), a1 = fval<F + 1>(z), a2 = fval<F + 2>(z), a3 = fval<F + 3>(z);
  float a4 = fval<F + 4>(z), a5 = fval<F + 5>(z), a6 = fval<F + 6>(z), a7 = fval<F + 7>(z);
  uint4 v;
  v.x = pk_bf16(a0, a1);
  v.y = pk_bf16(a2, a3);
  v.z = pk_bf16(a4, a5);
  v.w = pk_bf16(a6, a7);
  *(uint4*)dst = v;
}

// One 64-feature chunk: produce (own row, wave-private LDS slice) then consume (MFMA).
// No barrier needed: each wave reads only rows written by its own lanes, and
// per-wave DS ops execute in program order in the LDS pipe.
template <int C>
__device__ __forceinline__ void chunk_step(const float* z,
                                           char* aRow,
                                           const char* aRead,
                                           const char* bRead,
                                           f32x4 (&acc)[4]) {
  emit8<C * CHUNK + 0>(z, aRow + 0);
  emit8<C * CHUNK + 8>(z, aRow + 16);
  emit8<C * CHUNK + 16>(z, aRow + 32);
  emit8<C * CHUNK + 24>(z, aRow + 48);
  emit8<C * CHUNK + 32>(z, aRow + 64);
  emit8<C * CHUNK + 40>(z, aRow + 80);
  emit8<C * CHUNK + 48>(z, aRow + 96);
  emit8<C * CHUNK + 56>(z, aRow + 112);
  asm volatile("" ::: "memory");   // compile-time fence: writes above, reads below
#pragma unroll
  for (int t = 0; t < CHUNK / 32; ++t) {
    short8 bf = *(const short8*)(bRead + C * (CHUNK * 2) + t * 64);
#pragma unroll
    for (int m = 0; m < 4; ++m) {
      short8 af = *(const short8*)(aRead + m * 16 * A_STRIDE + t * 64);
      acc[m] = __builtin_amdgcn_mfma_f32_16x16x32_bf16(af, bf, acc[m], 0, 0, 0);
    }
  }
}

template <int C>
struct Chunks {
  static __device__ __forceinline__ void run(const float* z, char* aRow,
                                             const char* aRead, const char* bRead,
                                             f32x4 (&acc)[4]) {
    chunk_step<C>(z, aRow, aRead, bRead, acc);
    Chunks<C + 1>::run(z, aRow, aRead, bRead, acc);
  }
};
template <>
struct Chunks<NCHUNK> {
  static __device__ __forceinline__ void run(const float*, char*, const char*, const char*,
                                             f32x4 (&)[4]) {}
};

// ---- prep: coeffs_full = where(mask, fixed, coeff), transposed + bf16 + K-pad ----
// bt[col][k] = cf[k][col], k<969 else 0.  Identity feature<->coeff-row map; any
// hw-internal k permutation cancels because A and B use identical k addressing.
__global__ __launch_bounds__(256) void prep_bt(const float* __restrict__ coeff,
                                               const float* __restrict__ fixedv,
                                               const unsigned char* __restrict__ mask,
                                               unsigned short* __restrict__ bt) {
  int e = blockIdx.x * 256 + threadIdx.x;   // 0 .. 16383
  if (e >= DD * KPAD) return;
  int col = e >> 10, k = e & (KPAD - 1);
  float v = 0.0f;
  if (k < LIB) {
    int idx = k * DD + col;
    v = mask[idx] ? fixedv[idx] : coeff[idx];
  }
  unsigned int u = __builtin_bit_cast(unsigned int, v);
  u += 0x7fffu + ((u >> 16) & 1u);
  bt[e] = (unsigned short)(u >> 16);
}

__global__ __launch_bounds__(256, 2) void sindy_mfma(const float* __restrict__ z,
                                                     const unsigned short* __restrict__ bt,
                                                     float* __restrict__ out) {
  extern __shared__ char smem[];
  char* aBase = smem;
  char* bBase = smem + A_BYTES;
  const int tid = threadIdx.x;
  const int lane = tid & 63;
  const int w = tid >> 6;
  const long long row = (long long)blockIdx.x * 256 + tid;

  // stage B (16 x 1024 bf16) into LDS, padded row stride
  {
#pragma unroll
    for (int i = 0; i < 8; ++i) {
      int g4 = tid + i * 256;              // 0 .. 2047 (uint4 index)
      int col = g4 >> 7;                   // 128 uint4 per col
      int kk = g4 & 127;
      *(uint4*)(bBase + col * B_STRIDE + kk * 16) = ((const uint4*)bt)[g4];
    }
  }

  float zr[16];
  if (row < BATCH) {
    const float4* zp = (const float4*)(z + row * DD);
    float4 z0 = zp[0], z1 = zp[1], z2 = zp[2], z3 = zp[3];
    zr[0] = z0.x; zr[1] = z0.y; zr[2] = z0.z; zr[3] = z0.w;
    zr[4] = z1.x; zr[5] = z1.y; zr[6] = z1.z; zr[7] = z1.w;
    zr[8] = z2.x; zr[9] = z2.y; zr[10] = z2.z; zr[11] = z2.w;
    zr[12] = z3.x; zr[13] = z3.y; zr[14] = z3.z; zr[15] = z3.w;
  } else {
#pragma unroll
    for (int i = 0; i < 16; ++i) zr[i] = 0.0f;
  }
  __syncthreads();   // B visible to all waves (only barrier in the kernel)

  f32x4 acc[4] = {f32x4{0.f, 0.f, 0.f, 0.f}, f32x4{0.f, 0.f, 0.f, 0.f},
                  f32x4{0.f, 0.f, 0.f, 0.f}, f32x4{0.f, 0.f, 0.f, 0.f}};
  char* aRow = aBase + tid * A_STRIDE;                                   // producer: own row
  const char* aRead = aBase + (w * 64 + (lane & 15)) * A_STRIDE + (lane >> 4) * 16;
  const char* bRead = bBase + (lane & 15) * B_STRIDE + (lane >> 4) * 16;

  Chunks<0>::run(zr, aRow, aRead, bRead, acc);

  // C/D layout (m89/m91 verified): col = lane&15, row = 4*(lane>>4)+q
  const long long obase = (long long)blockIdx.x * 256 + w * 64;
  const int col = lane & 15;
#pragma unroll
  for (int m = 0; m < 4; ++m) {
#pragma unroll
    for (int q = 0; q < 4; ++q) {
      long long r = obase + m * 16 + (lane >> 4) * 4 + q;
      if (r < BATCH) out[r * DD + col] = acc[m][q];
    }
  }
}

extern "C" void kernel_launch(void* const* d_in, const int* in_sizes, int n_in,
                              void* d_out, int out_size, void* d_ws, size_t ws_size,
                              hipStream_t stream) {
  const float* z = (const float*)d_in[0];
  const float* coeff = (const float*)d_in[1];
  const float* fixedv = (const float*)d_in[2];
  const unsigned char* mask = (const unsigned char*)d_in[3];
  float* out = (float*)d_out;
  unsigned short* bt = (unsigned short*)d_ws;   // 16*1024*2 = 32768 B

  prep_bt<<<(DD * KPAD + 255) / 256, 256, 0, stream>>>(coeff, fixedv, mask, bt);

  const int nblk = (BATCH + 255) / 256;   // 782
  sindy_mfma<<<nblk, 256, LDS_BYTES, stream>>>(z, bt, out);
}